// Round 1
// baseline (96.828 us; speedup 1.0000x reference)
//
#include <hip/hip_runtime.h>

#define ALPHA1 1.2566f
#define ALPHA2 1.5f
#define ALPHA3 0.9f
#define S_STAR 20.0f
#define TAU    4.0f

// ---------------------------------------------------------------------------
// Setup: fold the purely-linear MLP into a single affine map.
//   M (5x6)  = W3 @ W2 @ W1         (row-major, ws[0..29])
//   c (5)    = b3 + W3 @ (b2 + W2 @ b1)   (ws[30..34])
// Cost ~33K FMA, one small block, negligible.
// ---------------------------------------------------------------------------
__global__ __launch_bounds__(256) void setup_kernel(
        const float* __restrict__ W1, const float* __restrict__ b1,
        const float* __restrict__ W2, const float* __restrict__ b2,
        const float* __restrict__ W3, const float* __restrict__ b3,
        float* __restrict__ ws) {
    __shared__ float T[100][6];   // W2 @ W1  (100x6)
    __shared__ float c2[100];     // b2 + W2 @ b1
    const int tid = threadIdx.x;

    for (int idx = tid; idx < 600; idx += blockDim.x) {
        const int i = idx / 6, k = idx % 6;
        float s = 0.f;
        #pragma unroll 10
        for (int h = 0; h < 50; ++h) s += W2[i * 50 + h] * W1[h * 6 + k];
        T[i][k] = s;
    }
    for (int i = tid; i < 100; i += blockDim.x) {
        float s = b2[i];
        #pragma unroll 10
        for (int h = 0; h < 50; ++h) s += W2[i * 50 + h] * b1[h];
        c2[i] = s;
    }
    __syncthreads();
    for (int idx = tid; idx < 30; idx += blockDim.x) {
        const int m = idx / 6, k = idx % 6;
        float s = 0.f;
        #pragma unroll 10
        for (int i = 0; i < 100; ++i) s += W3[m * 100 + i] * T[i][k];
        ws[idx] = s;
    }
    for (int m = tid; m < 5; m += blockDim.x) {
        float s = b3[m];
        #pragma unroll 10
        for (int i = 0; i < 100; ++i) s += W3[m * 100 + i] * c2[i];
        ws[30 + m] = s;
    }
}

// ---------------------------------------------------------------------------
// Main: per index j compute u = M @ z[j] + c, then the barrier math on the
// column view X[i][j] = z_flat[i*B + j]. 4 j's per thread via float4.
// ---------------------------------------------------------------------------
__global__ __launch_bounds__(256) void main_kernel(
        const float* __restrict__ z, const float* __restrict__ ws,
        float* __restrict__ out, int B4, long long B) {
    const long long t = (long long)blockIdx.x * blockDim.x + threadIdx.x;
    if (t >= B4) return;
    const long long j0 = t * 4;

    // Folded affine map (uniform address -> scalar loads / L1 broadcast).
    float M[4][6], c[4];
    #pragma unroll
    for (int m = 0; m < 4; ++m) {
        #pragma unroll
        for (int k = 0; k < 6; ++k) M[m][k] = ws[m * 6 + k];
        c[m] = ws[30 + m];
    }

    // Row view: z[j,0..5] for j = j0..j0+3 -> 24 contiguous floats.
    float zz[24];
    const float4* zr = (const float4*)(z + j0 * 6);
    #pragma unroll
    for (int v = 0; v < 6; ++v) {
        const float4 q = zr[v];
        zz[4 * v + 0] = q.x; zz[4 * v + 1] = q.y;
        zz[4 * v + 2] = q.z; zz[4 * v + 3] = q.w;
    }

    // Column view: X[i][j] = z_flat[i*B + j], 6 coalesced streams.
    float X[6][4];
    #pragma unroll
    for (int i = 0; i < 6; ++i) {
        const float4 q = *(const float4*)(z + (long long)i * B + j0);
        X[i][0] = q.x; X[i][1] = q.y; X[i][2] = q.z; X[i][3] = q.w;
    }

    // d3u = d3 @ f (constant vector)
    const float g1 = TAU * ALPHA3;                    //  3.6
    const float g2 = TAU * ALPHA1;
    const float g3 = 1.f - TAU * ALPHA2 - TAU * ALPHA3;
    const float g4 = -TAU * ALPHA1;
    const float g5 = TAU * ALPHA2 - 1.f;

    float4 o;
    float* op = &o.x;
    #pragma unroll
    for (int r = 0; r < 4; ++r) {
        float u[4];
        #pragma unroll
        for (int m = 0; m < 4; ++m) {
            float s = c[m];
            #pragma unroll
            for (int k = 0; k < 6; ++k) s = fmaf(M[m][k], zz[r * 6 + k], s);
            u[m] = s;
        }
        const float x1 = X[1][r], x2 = X[2][r], x3 = X[3][r];
        const float x4 = X[4][r], x5 = X[5][r];

        // fX rows (fX[1] == 0)
        const float fx2 = x1 - x3;
        const float fx3 = ALPHA3 * x1 + ALPHA1 * x2 - ALPHA2 * x3;
        const float fx4 = x3 - x5;
        const float fx5 = ALPHA3 * x3 + ALPHA1 * x4 - ALPHA2 * x5;

        const float eta1 = x2 + S_STAR - TAU * (x3 - x1);
        const float bb1  = (fx2 - TAU * fx3) + u[1] * eta1;   // d2@fX + p1*eta1

        const float eta2a = x4 + S_STAR - TAU * (x5 - x3);
        const float eta2b = g1 * x1 + g2 * x2 + g3 * x3 + g4 * x4 + g5 * x5;
        const float d3ufX = g2 * fx2 + g3 * fx3 + g4 * fx4 + g5 * fx5;
        const float bb2   = d3ufX + u[2] * eta2a + u[3] * eta2b;

        // A = [-TAU, -TAU*ALPHA3], both negative -> lb = max(ratios), ub = +inf
        const float r1 = bb1 / (-TAU);
        const float r2 = bb2 / (-(TAU * ALPHA3));
        const float lb = fmaxf(r1, r2);
        const float xu = 2.f * u[0];
        op[r] = fminf(fmaxf(xu, lb), 1e30f);
    }
    *(float4*)(out + j0) = o;
}

extern "C" void kernel_launch(void* const* d_in, const int* in_sizes, int n_in,
                              void* d_out, int out_size, void* d_ws, size_t ws_size,
                              hipStream_t stream) {
    const float* z  = (const float*)d_in[0];
    // d_in[1] = tilde_vh (unused by the reference output)
    const float* W1 = (const float*)d_in[2];
    const float* b1 = (const float*)d_in[3];
    const float* W2 = (const float*)d_in[4];
    const float* b2 = (const float*)d_in[5];
    const float* W3 = (const float*)d_in[6];
    const float* b3 = (const float*)d_in[7];
    float* out = (float*)d_out;
    float* ws  = (float*)d_ws;

    const long long B = (long long)in_sizes[0] / 6;

    setup_kernel<<<1, 256, 0, stream>>>(W1, b1, W2, b2, W3, b3, ws);

    const int B4 = (int)(B / 4);            // B = 1048576, divisible by 4
    const int threads = 256;
    const int blocks = (B4 + threads - 1) / threads;
    main_kernel<<<blocks, threads, 0, stream>>>(z, ws, out, B4, B);
}

// Round 2
// 93.045 us; speedup vs baseline: 1.0407x; 1.0407x over previous
//
#include <hip/hip_runtime.h>

#define ALPHA1 1.2566f
#define ALPHA2 1.5f
#define ALPHA3 0.9f
#define S_STAR 20.0f
#define TAU    4.0f

constexpr int TPB = 256;

// One fused kernel:
//   Phase 1 (per block, redundant): fold the purely-linear MLP
//     V (4x50) = W3[0:4] @ W2
//     M (4x6)  = V @ W1
//     c (4)    = b3 + W3 @ b2 + V @ b1
//   Phase 2: grid-strided streaming of the barrier math, 8 j's per thread
//   as two lane-contiguous float4 chunks.
__global__ __launch_bounds__(TPB) void fused_kernel(
        const float* __restrict__ z,
        const float* __restrict__ W1, const float* __restrict__ b1,
        const float* __restrict__ W2, const float* __restrict__ b2,
        const float* __restrict__ W3, const float* __restrict__ b3,
        float* __restrict__ out, long long B) {
    __shared__ float Vs[4][52];   // +2 pad
    __shared__ float Ms[4][6];
    __shared__ float cs[4];
    const int tid = threadIdx.x;

    // ---- Phase 1: weight fold (threads 0..199 for V; 0..27 for M,c) ----
    if (tid < 200) {
        const int m = tid / 50, h = tid % 50;   // W3 row broadcast, W2 col coalesced
        float s = 0.f;
        #pragma unroll 10
        for (int i = 0; i < 100; ++i)
            s = fmaf(W3[m * 100 + i], W2[i * 50 + h], s);
        Vs[m][h] = s;
    }
    __syncthreads();
    if (tid < 24) {
        const int m = tid / 6, k = tid % 6;
        float s = 0.f;
        #pragma unroll 10
        for (int h = 0; h < 50; ++h)
            s = fmaf(Vs[m][h], W1[h * 6 + k], s);
        Ms[m][k] = s;
    } else if (tid < 28) {
        const int m = tid - 24;
        float s = b3[m];
        #pragma unroll 10
        for (int i = 0; i < 100; ++i)
            s = fmaf(W3[m * 100 + i], b2[i], s);
        #pragma unroll 10
        for (int h = 0; h < 50; ++h)
            s = fmaf(Vs[m][h], b1[h], s);
        cs[m] = s;
    }
    __syncthreads();

    float M[4][6], c[4];
    #pragma unroll
    for (int m = 0; m < 4; ++m) {
        #pragma unroll
        for (int k = 0; k < 6; ++k) M[m][k] = Ms[m][k];
        c[m] = cs[m];
    }

    // d3u = d3 @ f (compile-time constants)
    const float g1 = TAU * ALPHA3;
    const float g2 = TAU * ALPHA1;
    const float g3 = 1.f - TAU * ALPHA2 - TAU * ALPHA3;
    const float g4 = -TAU * ALPHA1;
    const float g5 = TAU * ALPHA2 - 1.f;

    // ---- Phase 2: two float4 chunks per thread, lane-contiguous ----
    #pragma unroll
    for (int s2 = 0; s2 < 2; ++s2) {
        const long long j0 =
            ((long long)blockIdx.x * (2 * TPB) + s2 * TPB + tid) * 4;

        // Row view: z[j,0..5] for 4 consecutive j -> 96B contiguous.
        float zz[24];
        const float4* zr = (const float4*)(z + j0 * 6);
        #pragma unroll
        for (int v = 0; v < 6; ++v) {
            const float4 q = zr[v];
            zz[4 * v + 0] = q.x; zz[4 * v + 1] = q.y;
            zz[4 * v + 2] = q.z; zz[4 * v + 3] = q.w;
        }

        // Column view: X[i][j] = z_flat[i*B + j], 6 coalesced streams.
        float X[6][4];
        #pragma unroll
        for (int i = 0; i < 6; ++i) {
            const float4 q = *(const float4*)(z + (long long)i * B + j0);
            X[i][0] = q.x; X[i][1] = q.y; X[i][2] = q.z; X[i][3] = q.w;
        }

        float4 o;
        float* op = &o.x;
        #pragma unroll
        for (int r = 0; r < 4; ++r) {
            float u[4];
            #pragma unroll
            for (int m = 0; m < 4; ++m) {
                float s = c[m];
                #pragma unroll
                for (int k = 0; k < 6; ++k) s = fmaf(M[m][k], zz[r * 6 + k], s);
                u[m] = s;
            }
            const float x1 = X[1][r], x2 = X[2][r], x3 = X[3][r];
            const float x4 = X[4][r], x5 = X[5][r];

            const float fx2 = x1 - x3;
            const float fx3 = ALPHA3 * x1 + ALPHA1 * x2 - ALPHA2 * x3;
            const float fx4 = x3 - x5;
            const float fx5 = ALPHA3 * x3 + ALPHA1 * x4 - ALPHA2 * x5;

            const float eta1 = x2 + S_STAR - TAU * (x3 - x1);
            const float bb1  = (fx2 - TAU * fx3) + u[1] * eta1;

            const float eta2a = x4 + S_STAR - TAU * (x5 - x3);
            const float eta2b = g1 * x1 + g2 * x2 + g3 * x3 + g4 * x4 + g5 * x5;
            const float d3ufX = g2 * fx2 + g3 * fx3 + g4 * fx4 + g5 * fx5;
            const float bb2   = d3ufX + u[2] * eta2a + u[3] * eta2b;

            const float r1 = bb1 / (-TAU);
            const float r2 = bb2 / (-(TAU * ALPHA3));
            const float lb = fmaxf(r1, r2);
            const float xu = 2.f * u[0];
            op[r] = fminf(fmaxf(xu, lb), 1e30f);
        }
        *(float4*)(out + j0) = o;
    }
}

extern "C" void kernel_launch(void* const* d_in, const int* in_sizes, int n_in,
                              void* d_out, int out_size, void* d_ws, size_t ws_size,
                              hipStream_t stream) {
    const float* z  = (const float*)d_in[0];
    // d_in[1] = tilde_vh (unused by the reference output)
    const float* W1 = (const float*)d_in[2];
    const float* b1 = (const float*)d_in[3];
    const float* W2 = (const float*)d_in[4];
    const float* b2 = (const float*)d_in[5];
    const float* W3 = (const float*)d_in[6];
    const float* b3 = (const float*)d_in[7];
    float* out = (float*)d_out;

    const long long B = (long long)in_sizes[0] / 6;   // 1048576

    // chunks of 4 j's: B/4 total; 2*TPB chunks per block.
    const int blocks = (int)(B / (4LL * 2 * TPB));    // 512
    fused_kernel<<<blocks, TPB, 0, stream>>>(z, W1, b1, W2, b2, W3, b3, out, B);
}